// Round 1
// baseline (6811.506 us; speedup 1.0000x reference)
//
#include <hip/hip_runtime.h>
#include <cstddef>

#define NN 50000
#define NE 600000

// ---------------------------------------------------------------- preproc
// h0[n][c] = relu(sum_k x[n][k] * W[k][c] + b[c]),  k<16, c<32
__global__ __launch_bounds__(256)
void preproc_kernel(const float* __restrict__ x, const float* __restrict__ W,
                    const float* __restrict__ b, float* __restrict__ out)
{
    __shared__ float Wl[512];
    __shared__ float bl[32];
    int tx = threadIdx.x;
    Wl[tx]       = W[tx];
    Wl[tx + 256] = W[tx + 256];
    if (tx < 32) bl[tx] = b[tx];
    __syncthreads();
    int n = blockIdx.x * 256 + tx;
    if (n >= NN) return;
    float xr[16];
    const float4* xp = (const float4*)(x + (size_t)n * 16);
#pragma unroll
    for (int q = 0; q < 4; ++q) {
        float4 v = xp[q];
        xr[q*4+0]=v.x; xr[q*4+1]=v.y; xr[q*4+2]=v.z; xr[q*4+3]=v.w;
    }
    float acc[32];
#pragma unroll
    for (int c = 0; c < 32; ++c) acc[c] = bl[c];
#pragma unroll
    for (int k = 0; k < 16; ++k) {
#pragma unroll
        for (int c = 0; c < 32; ++c)
            acc[c] = fmaf(xr[k], Wl[k*32+c], acc[c]);
    }
    float4* op = (float4*)(out + (size_t)n * 32);
#pragma unroll
    for (int q = 0; q < 8; ++q) {
        float4 v;
        v.x = fmaxf(acc[q*4+0], 0.f);
        v.y = fmaxf(acc[q*4+1], 0.f);
        v.z = fmaxf(acc[q*4+2], 0.f);
        v.w = fmaxf(acc[q*4+3], 0.f);
        op[q] = v;
    }
}

// ---------------------------------------------------------------- gemm128
// out[n][c] = act( A1[n][:]@W1[:,c] + A2'[n][:]@W2[:,c] + outb[c] ), c<128
// A2'[n][k] = relu(A2[n][k] + inb2[k]) if inb2 else A2[n][k]
// Block tile 128x128, thread tile 8x8, K chunked by 32 with LDS staging.
__global__ __launch_bounds__(256, 4)
void gemm128(const float* __restrict__ A1, const float* __restrict__ W1, int K1,
             const float* __restrict__ A2, const float* __restrict__ W2, int K2,
             const float* __restrict__ inb2, const float* __restrict__ outb,
             int do_relu, float* __restrict__ out, int nrows)
{
    __shared__ float At[32][132];   // transposed A tile: At[k][node], pad->132
    __shared__ float Wl[32][128];   // W chunk, row-major
    const int tx = threadIdx.x;
    const int bm = blockIdx.x * 128;
    const int c0 = (tx & 15) * 8;
    const int n0 = (tx >> 4) * 8;
    float acc[8][8];
#pragma unroll
    for (int i = 0; i < 8; ++i)
#pragma unroll
        for (int j = 0; j < 8; ++j) acc[i][j] = 0.f;

    const int Ktot = K1 + K2;
    for (int k0 = 0; k0 < Ktot; k0 += 32) {
        const float* A; const float* W; const float* ib; int kk, Ka;
        if (k0 < K1) { A = A1; W = W1; kk = k0;      Ka = K1; ib = nullptr; }
        else         { A = A2; W = W2; kk = k0 - K1; Ka = K2; ib = inb2;  }
        // stage A: 128 rows x 32 k, stored transposed
#pragma unroll
        for (int it = 0; it < 4; ++it) {
            int idx = tx + it * 256;       // 0..1023
            int r = idx >> 3;              // node within tile (0..127)
            int q = idx & 7;               // float4 within 32-float chunk
            int n = bm + r;
            float4 v = make_float4(0.f, 0.f, 0.f, 0.f);
            if (n < nrows) v = *(const float4*)(A + (size_t)n * Ka + kk + q * 4);
            if (ib) {
                v.x = fmaxf(v.x + ib[kk + q*4 + 0], 0.f);
                v.y = fmaxf(v.y + ib[kk + q*4 + 1], 0.f);
                v.z = fmaxf(v.z + ib[kk + q*4 + 2], 0.f);
                v.w = fmaxf(v.w + ib[kk + q*4 + 3], 0.f);
            }
            At[q*4+0][r] = v.x;
            At[q*4+1][r] = v.y;
            At[q*4+2][r] = v.z;
            At[q*4+3][r] = v.w;
        }
        // stage W: 32 rows x 128 cols
#pragma unroll
        for (int it = 0; it < 4; ++it) {
            int idx = tx + it * 256;       // 0..1023
            int r = idx >> 5;              // k row (0..31)
            int q = idx & 31;              // float4 within 128-col row
            *(float4*)(&Wl[r][q*4]) = *(const float4*)(W + (size_t)(kk + r) * 128 + q * 4);
        }
        __syncthreads();
#pragma unroll 4
        for (int k = 0; k < 32; ++k) {
            float4 a0 = *(const float4*)(&At[k][n0]);
            float4 a1 = *(const float4*)(&At[k][n0 + 4]);
            float4 w0 = *(const float4*)(&Wl[k][c0]);
            float4 w1 = *(const float4*)(&Wl[k][c0 + 4]);
            float av[8] = {a0.x,a0.y,a0.z,a0.w,a1.x,a1.y,a1.z,a1.w};
            float wv[8] = {w0.x,w0.y,w0.z,w0.w,w1.x,w1.y,w1.z,w1.w};
#pragma unroll
            for (int i = 0; i < 8; ++i)
#pragma unroll
                for (int j = 0; j < 8; ++j)
                    acc[i][j] = fmaf(av[i], wv[j], acc[i][j]);
        }
        __syncthreads();
    }
    // epilogue
    float bb[8];
#pragma unroll
    for (int j = 0; j < 8; ++j) bb[j] = outb ? outb[c0 + j] : 0.f;
#pragma unroll
    for (int i = 0; i < 8; ++i) {
        int n = bm + n0 + i;
        if (n < nrows) {
            float4 o0, o1;
            o0.x = acc[i][0] + bb[0]; o0.y = acc[i][1] + bb[1];
            o0.z = acc[i][2] + bb[2]; o0.w = acc[i][3] + bb[3];
            o1.x = acc[i][4] + bb[4]; o1.y = acc[i][5] + bb[5];
            o1.z = acc[i][6] + bb[6]; o1.w = acc[i][7] + bb[7];
            if (do_relu) {
                o0.x = fmaxf(o0.x, 0.f); o0.y = fmaxf(o0.y, 0.f);
                o0.z = fmaxf(o0.z, 0.f); o0.w = fmaxf(o0.w, 0.f);
                o1.x = fmaxf(o1.x, 0.f); o1.y = fmaxf(o1.y, 0.f);
                o1.z = fmaxf(o1.z, 0.f); o1.w = fmaxf(o1.w, 0.f);
            }
            float4* po = (float4*)(out + (size_t)n * 128 + c0);
            po[0] = o0; po[1] = o1;
        }
    }
}

// ---------------------------------------------------------------- scatter
// agg[dst[e]][c] += hw[src[e]][c] * w[e]   (32 threads/edge, 4 ch each)
__global__ __launch_bounds__(256)
void scatter_add(const float* __restrict__ hw, const int* __restrict__ src,
                 const int* __restrict__ dst, const float* __restrict__ wgt,
                 float* __restrict__ agg)
{
    long long t = (long long)blockIdx.x * 256 + threadIdx.x;
    int e = (int)(t >> 5);
    if (e >= NE) return;
    int lane = (int)(t & 31);
    int s = src[e], d = dst[e];
    float w = wgt[e];
    float4 v = *(const float4*)(hw + (size_t)s * 128 + lane * 4);
    float* ap = agg + (size_t)d * 128 + lane * 4;
    atomicAdd(ap + 0, v.x * w);
    atomicAdd(ap + 1, v.y * w);
    atomicAdd(ap + 2, v.z * w);
    atomicAdd(ap + 3, v.w * w);
}

// ---------------------------------------------------------------- last2
// out[n][l] = sigmoid(h[n][:] @ W[:,l] + b[l]),  l<2
__global__ __launch_bounds__(256)
void last2_kernel(const float* __restrict__ h, const float* __restrict__ W,
                  const float* __restrict__ b, float* __restrict__ out)
{
    int t = blockIdx.x * 256 + threadIdx.x;
    int n = t >> 1, l = t & 1;
    if (n >= NN) return;
    float s = 0.f;
    const float* hp = h + (size_t)n * 128;
#pragma unroll 8
    for (int k = 0; k < 128; ++k) s = fmaf(hp[k], W[k*2 + l], s);
    s += b[l];
    out[(size_t)n*2 + l] = 1.f / (1.f + __expf(-s));
}

// ---------------------------------------------------------------- launch
extern "C" void kernel_launch(void* const* d_in, const int* in_sizes, int n_in,
                              void* d_out, int out_size, void* d_ws, size_t ws_size,
                              hipStream_t stream)
{
    const float* x    = (const float*)d_in[0];
    const int*   esrc = (const int*)  d_in[1];
    const int*   edst = (const int*)  d_in[2];
    const float* ew   = (const float*)d_in[3];
    const float* preW = (const float*)d_in[4];
    const float* preb = (const float*)d_in[5];
    const float* f1W  = (const float*)d_in[6];
    const float* f1b  = (const float*)d_in[7];
    const float* f2W  = (const float*)d_in[8];
    const float* f2b  = (const float*)d_in[9];
    const float* gW   = (const float*)d_in[10];
    const float* gb   = (const float*)d_in[11];
    const float* fgW  = (const float*)d_in[12];
    const float* fgb  = (const float*)d_in[13];
    const float* l1W  = (const float*)d_in[14];
    const float* l1b  = (const float*)d_in[15];
    const float* l2W  = (const float*)d_in[16];
    const float* l2b  = (const float*)d_in[17];
    float* out = (float*)d_out;

    float* ws  = (float*)d_ws;
    float* h0  = ws;                         // N*32
    float* nid = h0  + (size_t)NN * 32;      // N*128
    float* h   = nid + (size_t)NN * 128;     // N*128
    float* hw  = h   + (size_t)NN * 128;     // N*128
    float* agg = hw  + (size_t)NN * 128;     // N*128

    const int gblocks = (NN + 127) / 128;    // 391

    preproc_kernel<<<(NN + 255) / 256, 256, 0, stream>>>(x, preW, preb, h0);
    gemm128<<<gblocks, 256, 0, stream>>>(h0, f1W, 32, nullptr, nullptr, 0,
                                         nullptr, f1b, 1, nid, NN);
    gemm128<<<gblocks, 256, 0, stream>>>(h0, f2W, 32, nullptr, nullptr, 0,
                                         nullptr, f2b, 1, h, NN);
    for (int l = 0; l < 6; ++l) {
        // hw = h @ gcn_W[l]   (no bias, no relu — applied after aggregation)
        gemm128<<<gblocks, 256, 0, stream>>>(h, gW + (size_t)l*128*128, 128,
                                             nullptr, nullptr, 0,
                                             nullptr, nullptr, 0, hw, NN);
        hipMemsetAsync(agg, 0, (size_t)NN * 128 * sizeof(float), stream);
        scatter_add<<<(int)(((long long)NE*32 + 255) / 256), 256, 0, stream>>>(
            hw, esrc, edst, ew, agg);
        // h = relu( nid @ Wf_top + relu(agg + gcn_b[l]) @ Wf_bot + fcg_b[l] )
        gemm128<<<gblocks, 256, 0, stream>>>(nid, fgW + (size_t)l*256*128, 128,
                                             agg, fgW + (size_t)l*256*128 + 128*128, 128,
                                             gb + (size_t)l*128, fgb + (size_t)l*128,
                                             1, h, NN);
    }
    // tmp(hw) = relu( nid @ last1_top + h @ last1_bot + last1_b )
    gemm128<<<gblocks, 256, 0, stream>>>(nid, l1W, 128, h, l1W + 128*128, 128,
                                         nullptr, l1b, 1, hw, NN);
    last2_kernel<<<(NN*2 + 255) / 256, 256, 0, stream>>>(hw, l2W, l2b, out);
}

// Round 2
// 1107.733 us; speedup vs baseline: 6.1491x; 6.1491x over previous
//
#include <hip/hip_runtime.h>
#include <cstddef>

#define NN 50000
#define NE 600000
#define SCAN_BLOCKS ((NN + 1023) / 1024)   // 49

// ---------------------------------------------------------------- preproc
__global__ __launch_bounds__(256)
void preproc_kernel(const float* __restrict__ x, const float* __restrict__ W,
                    const float* __restrict__ b, float* __restrict__ out)
{
    __shared__ float Wl[512];
    __shared__ float bl[32];
    int tx = threadIdx.x;
    Wl[tx]       = W[tx];
    Wl[tx + 256] = W[tx + 256];
    if (tx < 32) bl[tx] = b[tx];
    __syncthreads();
    int n = blockIdx.x * 256 + tx;
    if (n >= NN) return;
    float xr[16];
    const float4* xp = (const float4*)(x + (size_t)n * 16);
#pragma unroll
    for (int q = 0; q < 4; ++q) {
        float4 v = xp[q];
        xr[q*4+0]=v.x; xr[q*4+1]=v.y; xr[q*4+2]=v.z; xr[q*4+3]=v.w;
    }
    float acc[32];
#pragma unroll
    for (int c = 0; c < 32; ++c) acc[c] = bl[c];
#pragma unroll
    for (int k = 0; k < 16; ++k) {
#pragma unroll
        for (int c = 0; c < 32; ++c)
            acc[c] = fmaf(xr[k], Wl[k*32+c], acc[c]);
    }
    float4* op = (float4*)(out + (size_t)n * 32);
#pragma unroll
    for (int q = 0; q < 8; ++q) {
        float4 v;
        v.x = fmaxf(acc[q*4+0], 0.f);
        v.y = fmaxf(acc[q*4+1], 0.f);
        v.z = fmaxf(acc[q*4+2], 0.f);
        v.w = fmaxf(acc[q*4+3], 0.f);
        op[q] = v;
    }
}

// ---------------------------------------------------------------- gemm128
// out[n][c] = act( A1@W1 + A2'@W2 + outb ), A2'[n][k]=relu(A2[n][k]+inb2[k])
__global__ __launch_bounds__(256, 4)
void gemm128(const float* __restrict__ A1, const float* __restrict__ W1, int K1,
             const float* __restrict__ A2, const float* __restrict__ W2, int K2,
             const float* __restrict__ inb2, const float* __restrict__ outb,
             int do_relu, float* __restrict__ out, int nrows)
{
    __shared__ float At[32][132];
    __shared__ float Wl[32][128];
    const int tx = threadIdx.x;
    const int bm = blockIdx.x * 128;
    const int c0 = (tx & 15) * 8;
    const int n0 = (tx >> 4) * 8;
    float acc[8][8];
#pragma unroll
    for (int i = 0; i < 8; ++i)
#pragma unroll
        for (int j = 0; j < 8; ++j) acc[i][j] = 0.f;

    const int Ktot = K1 + K2;
    for (int k0 = 0; k0 < Ktot; k0 += 32) {
        const float* A; const float* W; const float* ib; int kk, Ka;
        if (k0 < K1) { A = A1; W = W1; kk = k0;      Ka = K1; ib = nullptr; }
        else         { A = A2; W = W2; kk = k0 - K1; Ka = K2; ib = inb2;  }
#pragma unroll
        for (int it = 0; it < 4; ++it) {
            int idx = tx + it * 256;
            int r = idx >> 3;
            int q = idx & 7;
            int n = bm + r;
            float4 v = make_float4(0.f, 0.f, 0.f, 0.f);
            if (n < nrows) v = *(const float4*)(A + (size_t)n * Ka + kk + q * 4);
            if (ib) {
                v.x = fmaxf(v.x + ib[kk + q*4 + 0], 0.f);
                v.y = fmaxf(v.y + ib[kk + q*4 + 1], 0.f);
                v.z = fmaxf(v.z + ib[kk + q*4 + 2], 0.f);
                v.w = fmaxf(v.w + ib[kk + q*4 + 3], 0.f);
            }
            At[q*4+0][r] = v.x;
            At[q*4+1][r] = v.y;
            At[q*4+2][r] = v.z;
            At[q*4+3][r] = v.w;
        }
#pragma unroll
        for (int it = 0; it < 4; ++it) {
            int idx = tx + it * 256;
            int r = idx >> 5;
            int q = idx & 31;
            *(float4*)(&Wl[r][q*4]) = *(const float4*)(W + (size_t)(kk + r) * 128 + q * 4);
        }
        __syncthreads();
#pragma unroll 4
        for (int k = 0; k < 32; ++k) {
            float4 a0 = *(const float4*)(&At[k][n0]);
            float4 a1 = *(const float4*)(&At[k][n0 + 4]);
            float4 w0 = *(const float4*)(&Wl[k][c0]);
            float4 w1 = *(const float4*)(&Wl[k][c0 + 4]);
            float av[8] = {a0.x,a0.y,a0.z,a0.w,a1.x,a1.y,a1.z,a1.w};
            float wv[8] = {w0.x,w0.y,w0.z,w0.w,w1.x,w1.y,w1.z,w1.w};
#pragma unroll
            for (int i = 0; i < 8; ++i)
#pragma unroll
                for (int j = 0; j < 8; ++j)
                    acc[i][j] = fmaf(av[i], wv[j], acc[i][j]);
        }
        __syncthreads();
    }
    float bb[8];
#pragma unroll
    for (int j = 0; j < 8; ++j) bb[j] = outb ? outb[c0 + j] : 0.f;
#pragma unroll
    for (int i = 0; i < 8; ++i) {
        int n = bm + n0 + i;
        if (n < nrows) {
            float4 o0, o1;
            o0.x = acc[i][0] + bb[0]; o0.y = acc[i][1] + bb[1];
            o0.z = acc[i][2] + bb[2]; o0.w = acc[i][3] + bb[3];
            o1.x = acc[i][4] + bb[4]; o1.y = acc[i][5] + bb[5];
            o1.z = acc[i][6] + bb[6]; o1.w = acc[i][7] + bb[7];
            if (do_relu) {
                o0.x = fmaxf(o0.x, 0.f); o0.y = fmaxf(o0.y, 0.f);
                o0.z = fmaxf(o0.z, 0.f); o0.w = fmaxf(o0.w, 0.f);
                o1.x = fmaxf(o1.x, 0.f); o1.y = fmaxf(o1.y, 0.f);
                o1.z = fmaxf(o1.z, 0.f); o1.w = fmaxf(o1.w, 0.f);
            }
            float4* po = (float4*)(out + (size_t)n * 128 + c0);
            po[0] = o0; po[1] = o1;
        }
    }
}

// ---------------------------------------------------------------- CSR build
__global__ __launch_bounds__(256)
void hist_kernel(const int* __restrict__ dst, int* __restrict__ deg)
{
    int e = blockIdx.x * 256 + threadIdx.x;
    if (e < NE) atomicAdd(&deg[dst[e]], 1);
}

// exclusive scan, 3 kernels (chunk = 1024)
__global__ __launch_bounds__(1024)
void scan1_kernel(const int* __restrict__ deg, int* __restrict__ off,
                  int* __restrict__ bsum)
{
    __shared__ int buf[1024];
    int tx = threadIdx.x;
    int i = blockIdx.x * 1024 + tx;
    int v = (i < NN) ? deg[i] : 0;
    buf[tx] = v;
    __syncthreads();
    for (int s = 1; s < 1024; s <<= 1) {
        int t = (tx >= s) ? buf[tx - s] : 0;
        __syncthreads();
        buf[tx] += t;
        __syncthreads();
    }
    if (i < NN) off[i] = buf[tx] - v;            // block-local exclusive
    if (tx == 1023) bsum[blockIdx.x] = buf[1023];
}

__global__ __launch_bounds__(64)
void scan2_kernel(int* __restrict__ bsum)
{
    __shared__ int buf[64];
    int tx = threadIdx.x;
    int v = (tx < SCAN_BLOCKS) ? bsum[tx] : 0;
    buf[tx] = v;
    __syncthreads();
    for (int s = 1; s < 64; s <<= 1) {
        int t = (tx >= s) ? buf[tx - s] : 0;
        __syncthreads();
        buf[tx] += t;
        __syncthreads();
    }
    if (tx < SCAN_BLOCKS) bsum[tx] = buf[tx] - v;  // exclusive
}

__global__ __launch_bounds__(1024)
void scan3_kernel(int* __restrict__ off, const int* __restrict__ bsum)
{
    int i = blockIdx.x * 1024 + threadIdx.x;
    if (i < NN) off[i] += bsum[blockIdx.x];
    if (i == 0) off[NN] = NE;
}

__global__ __launch_bounds__(256)
void permute_kernel(const int* __restrict__ src, const int* __restrict__ dst,
                    const float* __restrict__ w, const int* __restrict__ off,
                    int* __restrict__ cursor, int* __restrict__ ssrc,
                    float* __restrict__ sw)
{
    int e = blockIdx.x * 256 + threadIdx.x;
    if (e >= NE) return;
    int d = dst[e];
    int p = off[d] + atomicAdd(&cursor[d], 1);
    ssrc[p] = src[e];
    sw[p]   = w[e];
}

// ---------------------------------------------------------------- gather agg
// 32 threads/node, 4 channels each; no atomics, no memset.
__global__ __launch_bounds__(256)
void gather_agg(const float* __restrict__ hw, const int* __restrict__ ssrc,
                const float* __restrict__ sw, const int* __restrict__ off,
                float* __restrict__ agg)
{
    long long t = (long long)blockIdx.x * 256 + threadIdx.x;
    int n = (int)(t >> 5);
    if (n >= NN) return;
    int lane = (int)(t & 31);
    int e0 = off[n], e1 = off[n + 1];
    float4 acc = make_float4(0.f, 0.f, 0.f, 0.f);
    for (int e = e0; e < e1; ++e) {
        int s   = ssrc[e];
        float w = sw[e];
        float4 v = *(const float4*)(hw + (size_t)s * 128 + lane * 4);
        acc.x = fmaf(v.x, w, acc.x);
        acc.y = fmaf(v.y, w, acc.y);
        acc.z = fmaf(v.z, w, acc.z);
        acc.w = fmaf(v.w, w, acc.w);
    }
    *(float4*)(agg + (size_t)n * 128 + lane * 4) = acc;
}

// ---------------------------------------------------------------- last2
__global__ __launch_bounds__(256)
void last2_kernel(const float* __restrict__ h, const float* __restrict__ W,
                  const float* __restrict__ b, float* __restrict__ out)
{
    int t = blockIdx.x * 256 + threadIdx.x;
    int n = t >> 1, l = t & 1;
    if (n >= NN) return;
    float s = 0.f;
    const float* hp = h + (size_t)n * 128;
#pragma unroll 8
    for (int k = 0; k < 128; ++k) s = fmaf(hp[k], W[k*2 + l], s);
    s += b[l];
    out[(size_t)n*2 + l] = 1.f / (1.f + __expf(-s));
}

// ---------------------------------------------------------------- launch
extern "C" void kernel_launch(void* const* d_in, const int* in_sizes, int n_in,
                              void* d_out, int out_size, void* d_ws, size_t ws_size,
                              hipStream_t stream)
{
    const float* x    = (const float*)d_in[0];
    const int*   esrc = (const int*)  d_in[1];
    const int*   edst = (const int*)  d_in[2];
    const float* ew   = (const float*)d_in[3];
    const float* preW = (const float*)d_in[4];
    const float* preb = (const float*)d_in[5];
    const float* f1W  = (const float*)d_in[6];
    const float* f1b  = (const float*)d_in[7];
    const float* f2W  = (const float*)d_in[8];
    const float* f2b  = (const float*)d_in[9];
    const float* gW   = (const float*)d_in[10];
    const float* gb   = (const float*)d_in[11];
    const float* fgW  = (const float*)d_in[12];
    const float* fgb  = (const float*)d_in[13];
    const float* l1W  = (const float*)d_in[14];
    const float* l1b  = (const float*)d_in[15];
    const float* l2W  = (const float*)d_in[16];
    const float* l2b  = (const float*)d_in[17];
    float* out = (float*)d_out;

    float* ws  = (float*)d_ws;
    float* h0  = ws;                         // N*32
    float* nid = h0  + (size_t)NN * 32;      // N*128
    float* h   = nid + (size_t)NN * 128;     // N*128
    float* hw  = h   + (size_t)NN * 128;     // N*128
    float* agg = hw  + (size_t)NN * 128;     // N*128
    float* sw  = agg + (size_t)NN * 128;     // E floats (dst-sorted weights)
    int*   ip  = (int*)(sw + NE);
    int*   deg    = ip;                      // N
    int*   off    = deg + NN;                // N+1
    int*   cursor = off + NN + 1;            // N
    int*   bsum   = cursor + NN;             // SCAN_BLOCKS (pad 64)
    int*   ssrc   = bsum + 64;               // E (dst-sorted sources)

    const int gblocks = (NN + 127) / 128;    // 391
    const int eblocks = (NE + 255) / 256;

    // ---- CSR build (once; reused by all 6 layers) ----
    hipMemsetAsync(deg, 0, (size_t)NN * sizeof(int), stream);
    hipMemsetAsync(cursor, 0, (size_t)NN * sizeof(int), stream);
    hist_kernel<<<eblocks, 256, 0, stream>>>(edst, deg);
    scan1_kernel<<<SCAN_BLOCKS, 1024, 0, stream>>>(deg, off, bsum);
    scan2_kernel<<<1, 64, 0, stream>>>(bsum);
    scan3_kernel<<<SCAN_BLOCKS, 1024, 0, stream>>>(off, bsum);
    permute_kernel<<<eblocks, 256, 0, stream>>>(esrc, edst, ew, off, cursor, ssrc, sw);

    // ---- network ----
    preproc_kernel<<<(NN + 255) / 256, 256, 0, stream>>>(x, preW, preb, h0);
    gemm128<<<gblocks, 256, 0, stream>>>(h0, f1W, 32, nullptr, nullptr, 0,
                                         nullptr, f1b, 1, nid, NN);
    gemm128<<<gblocks, 256, 0, stream>>>(h0, f2W, 32, nullptr, nullptr, 0,
                                         nullptr, f2b, 1, h, NN);
    for (int l = 0; l < 6; ++l) {
        gemm128<<<gblocks, 256, 0, stream>>>(h, gW + (size_t)l*128*128, 128,
                                             nullptr, nullptr, 0,
                                             nullptr, nullptr, 0, hw, NN);
        gather_agg<<<(int)(((long long)NN*32 + 255) / 256), 256, 0, stream>>>(
            hw, ssrc, sw, off, agg);
        gemm128<<<gblocks, 256, 0, stream>>>(nid, fgW + (size_t)l*256*128, 128,
                                             agg, fgW + (size_t)l*256*128 + 128*128, 128,
                                             gb + (size_t)l*128, fgb + (size_t)l*128,
                                             1, h, NN);
    }
    gemm128<<<gblocks, 256, 0, stream>>>(nid, l1W, 128, h, l1W + 128*128, 128,
                                         nullptr, l1b, 1, hw, NN);
    last2_kernel<<<(NN*2 + 255) / 256, 256, 0, stream>>>(hw, l2W, l2b, out);
}

// Round 3
// 638.941 us; speedup vs baseline: 10.6606x; 1.7337x over previous
//
#include <hip/hip_runtime.h>
#include <cstddef>
#include <cstdint>

#define NN 50000
#define NE 600000
#define SCAN_BLOCKS ((NN + 1023) / 1024)   // 49

typedef __attribute__((ext_vector_type(8))) short bf16x8;
typedef __attribute__((ext_vector_type(4))) float f32x4;

__device__ __forceinline__ float bf2f(ushort u) {
    return __uint_as_float(((uint32_t)u) << 16);
}
__device__ __forceinline__ ushort f2bf(float f) {   // round-to-nearest-even
    uint32_t b = __float_as_uint(f);
    return (ushort)((b + 0x7FFF + ((b >> 16) & 1)) >> 16);
}

// ---------------------------------------------------------------- weights->bf16 transposed
// Wt[c][k] layouts: wf1[128][32] wf2[128][32] wg[l][128][128] wfg[l][128][256] wl1[128][256]
__global__ __launch_bounds__(256)
void convert_weights(const float* __restrict__ f1W, const float* __restrict__ f2W,
                     const float* __restrict__ gW, const float* __restrict__ fgW,
                     const float* __restrict__ l1W, ushort* __restrict__ wt)
{
    int i = blockIdx.x * 256 + threadIdx.x;          // 0 .. 335871
    if (i >= 335872) return;
    float v;
    if (i < 4096) {                                  // wf1
        int c = i >> 5, k = i & 31;
        v = f1W[k * 128 + c];
    } else if (i < 8192) {                           // wf2
        int j = i - 4096; int c = j >> 5, k = j & 31;
        v = f2W[k * 128 + c];
    } else if (i < 8192 + 98304) {                   // wg
        int j = i - 8192; int l = j >> 14, r = j & 16383;
        int c = r >> 7, k = r & 127;
        v = gW[l * 16384 + k * 128 + c];
    } else if (i < 8192 + 98304 + 196608) {          // wfg
        int j = i - (8192 + 98304); int l = j >> 15, r = j & 32767;
        int c = r >> 8, k = r & 255;
        v = fgW[l * 32768 + k * 128 + c];
    } else {                                         // wl1
        int j = i - (8192 + 98304 + 196608);
        int c = j >> 8, k = j & 255;
        v = l1W[k * 128 + c];
    }
    wt[i] = f2bf(v);
}

// ---------------------------------------------------------------- preproc (out bf16)
__global__ __launch_bounds__(256)
void preproc_kernel(const float* __restrict__ x, const float* __restrict__ W,
                    const float* __restrict__ b, ushort* __restrict__ out)
{
    __shared__ float Wl[512];
    __shared__ float bl[32];
    int tx = threadIdx.x;
    Wl[tx]       = W[tx];
    Wl[tx + 256] = W[tx + 256];
    if (tx < 32) bl[tx] = b[tx];
    __syncthreads();
    int n = blockIdx.x * 256 + tx;
    if (n >= NN) return;
    float xr[16];
    const float4* xp = (const float4*)(x + (size_t)n * 16);
#pragma unroll
    for (int q = 0; q < 4; ++q) {
        float4 v = xp[q];
        xr[q*4+0]=v.x; xr[q*4+1]=v.y; xr[q*4+2]=v.z; xr[q*4+3]=v.w;
    }
    float acc[32];
#pragma unroll
    for (int c = 0; c < 32; ++c) acc[c] = bl[c];
#pragma unroll
    for (int k = 0; k < 16; ++k)
#pragma unroll
        for (int c = 0; c < 32; ++c)
            acc[c] = fmaf(xr[k], Wl[k*32+c], acc[c]);
    ushort4* op = (ushort4*)(out + (size_t)n * 32);
#pragma unroll
    for (int q = 0; q < 8; ++q) {
        ushort4 v;
        v.x = f2bf(fmaxf(acc[q*4+0], 0.f));
        v.y = f2bf(fmaxf(acc[q*4+1], 0.f));
        v.z = f2bf(fmaxf(acc[q*4+2], 0.f));
        v.w = f2bf(fmaxf(acc[q*4+3], 0.f));
        op[q] = v;
    }
}

// ---------------------------------------------------------------- MFMA GEMM
// out[n][c] = act( [A1|A2][n][:] @ Wt[c][:]^T + bias[c] ), c<128, bf16 in/out.
// Block: 64 rows x 128 cols, 4 waves (wave = 16 rows x 128 cols), BK=32.
// LDS tiles filled by global_load_lds (lane i -> base + 16*i); XOR chunk
// swizzle slot = q ^ ((r^(r>>2))&3) makes frag ds_read_b128 2-way (free).
__global__ __launch_bounds__(256)
void gemm_mfma(const ushort* __restrict__ A1, int K1,
               const ushort* __restrict__ A2, int K2,
               const ushort* __restrict__ Wt, const float* __restrict__ bias,
               int do_relu, ushort* __restrict__ out, int nrows)
{
    __shared__ ushort Atile[64 * 32];    // 4 KB
    __shared__ ushort Btile[128 * 32];   // 8 KB
    const int tx   = threadIdx.x;
    const int wave = tx >> 6;
    const int lane = tx & 63;
    const int bm   = blockIdx.x * 64;
    const int Ktot = K1 + K2;

    // store-side (per-lane global chunk selection)
    const int sr  = lane >> 2;                       // row within 16-row group
    const int sq  = lane & 3;                        // LDS slot
    const int chn = sq ^ ((sr ^ (sr >> 2)) & 3);     // global 16B-chunk index
    int arow = bm + wave * 16 + sr;                  // A row this lane fetches
    if (arow >= nrows) arow = nrows - 1;             // clamp (tail rows discarded)
    const int brow0 = wave * 32 + sr;                // B rows (two groups/wave)
    const int brow1 = wave * 32 + 16 + sr;

    // read-side (frag addressing)
    const int m    = lane & 15;
    const int quad = lane >> 4;
    const int slot = quad ^ ((m ^ (m >> 2)) & 3);

    f32x4 acc[8];
#pragma unroll
    for (int t = 0; t < 8; ++t) acc[t] = (f32x4){0.f, 0.f, 0.f, 0.f};

    for (int kk = 0; kk < Ktot; kk += 32) {
        const ushort* asrc; int astr, kl;
        if (kk < K1) { asrc = A1; astr = K1; kl = kk; }
        else         { asrc = A2; astr = K2; kl = kk - K1; }
        __builtin_amdgcn_global_load_lds(
            (const __attribute__((address_space(1))) void*)
                (asrc + (size_t)arow * astr + kl + chn * 8),
            (__attribute__((address_space(3))) void*)(Atile + wave * 512),
            16, 0, 0);
        __builtin_amdgcn_global_load_lds(
            (const __attribute__((address_space(1))) void*)
                (Wt + (size_t)brow0 * Ktot + kk + chn * 8),
            (__attribute__((address_space(3))) void*)(Btile + (2 * wave) * 512),
            16, 0, 0);
        __builtin_amdgcn_global_load_lds(
            (const __attribute__((address_space(1))) void*)
                (Wt + (size_t)brow1 * Ktot + kk + chn * 8),
            (__attribute__((address_space(3))) void*)(Btile + (2 * wave + 1) * 512),
            16, 0, 0);
        __syncthreads();
        bf16x8 af = *(const bf16x8*)(Atile + (wave * 16 + m) * 32 + slot * 8);
#pragma unroll
        for (int t = 0; t < 8; ++t) {
            bf16x8 bfr = *(const bf16x8*)(Btile + (t * 16 + m) * 32 + slot * 8);
            acc[t] = __builtin_amdgcn_mfma_f32_16x16x32_bf16(af, bfr, acc[t], 0, 0, 0);
        }
        __syncthreads();
    }

    // epilogue: C/D layout col=lane&15, row=quad*4+reg
    const int orow0 = bm + wave * 16 + quad * 4;
#pragma unroll
    for (int t = 0; t < 8; ++t) {
        int col = t * 16 + m;
        float bb = bias ? bias[col] : 0.f;
#pragma unroll
        for (int r = 0; r < 4; ++r) {
            int row = orow0 + r;
            if (row < nrows) {
                float v = acc[t][r] + bb;
                if (do_relu) v = fmaxf(v, 0.f);
                out[(size_t)row * 128 + col] = f2bf(v);
            }
        }
    }
}

// ---------------------------------------------------------------- CSR build
__global__ __launch_bounds__(256)
void hist_kernel(const int* __restrict__ dst, int* __restrict__ deg)
{
    int e = blockIdx.x * 256 + threadIdx.x;
    if (e < NE) atomicAdd(&deg[dst[e]], 1);
}

__global__ __launch_bounds__(1024)
void scan1_kernel(const int* __restrict__ deg, int* __restrict__ off,
                  int* __restrict__ bsum)
{
    __shared__ int buf[1024];
    int tx = threadIdx.x;
    int i = blockIdx.x * 1024 + tx;
    int v = (i < NN) ? deg[i] : 0;
    buf[tx] = v;
    __syncthreads();
    for (int s = 1; s < 1024; s <<= 1) {
        int t = (tx >= s) ? buf[tx - s] : 0;
        __syncthreads();
        buf[tx] += t;
        __syncthreads();
    }
    if (i < NN) off[i] = buf[tx] - v;
    if (tx == 1023) bsum[blockIdx.x] = buf[1023];
}

__global__ __launch_bounds__(64)
void scan2_kernel(int* __restrict__ bsum)
{
    __shared__ int buf[64];
    int tx = threadIdx.x;
    int v = (tx < SCAN_BLOCKS) ? bsum[tx] : 0;
    buf[tx] = v;
    __syncthreads();
    for (int s = 1; s < 64; s <<= 1) {
        int t = (tx >= s) ? buf[tx - s] : 0;
        __syncthreads();
        buf[tx] += t;
        __syncthreads();
    }
    if (tx < SCAN_BLOCKS) bsum[tx] = buf[tx] - v;
}

__global__ __launch_bounds__(1024)
void scan3_kernel(int* __restrict__ off, const int* __restrict__ bsum)
{
    int i = blockIdx.x * 1024 + threadIdx.x;
    if (i < NN) off[i] += bsum[blockIdx.x];
    if (i == 0) off[NN] = NE;
}

__global__ __launch_bounds__(256)
void permute_kernel(const int* __restrict__ src, const int* __restrict__ dst,
                    const float* __restrict__ w, const int* __restrict__ off,
                    int* __restrict__ cursor, int* __restrict__ ssrc,
                    float* __restrict__ sw)
{
    int e = blockIdx.x * 256 + threadIdx.x;
    if (e >= NE) return;
    int d = dst[e];
    int p = off[d] + atomicAdd(&cursor[d], 1);
    ssrc[p] = src[e];
    sw[p]   = w[e];
}

// ---------------------------------------------------------------- gather agg
// aggb[n][c] = bf16( relu( sum_e w[e]*hwb[src[e]][c] + gbias[c] ) )
__global__ __launch_bounds__(256)
void gather_agg(const ushort* __restrict__ hwb, const int* __restrict__ ssrc,
                const float* __restrict__ sw, const int* __restrict__ off,
                const float* __restrict__ gbias, ushort* __restrict__ aggb)
{
    long long t = (long long)blockIdx.x * 256 + threadIdx.x;
    int n = (int)(t >> 5);
    if (n >= NN) return;
    int lane = (int)(t & 31);
    int e0 = off[n], e1 = off[n + 1];
    float4 acc = make_float4(0.f, 0.f, 0.f, 0.f);
    for (int e = e0; e < e1; ++e) {
        int s   = ssrc[e];
        float w = sw[e];
        ushort4 v = *(const ushort4*)(hwb + (size_t)s * 128 + lane * 4);
        acc.x = fmaf(bf2f(v.x), w, acc.x);
        acc.y = fmaf(bf2f(v.y), w, acc.y);
        acc.z = fmaf(bf2f(v.z), w, acc.z);
        acc.w = fmaf(bf2f(v.w), w, acc.w);
    }
    int c0 = lane * 4;
    ushort4 o;
    o.x = f2bf(fmaxf(acc.x + gbias[c0 + 0], 0.f));
    o.y = f2bf(fmaxf(acc.y + gbias[c0 + 1], 0.f));
    o.z = f2bf(fmaxf(acc.z + gbias[c0 + 2], 0.f));
    o.w = f2bf(fmaxf(acc.w + gbias[c0 + 3], 0.f));
    *(ushort4*)(aggb + (size_t)n * 128 + c0) = o;
}

// ---------------------------------------------------------------- last2
__global__ __launch_bounds__(256)
void last2_kernel(const ushort* __restrict__ h, const float* __restrict__ W,
                  const float* __restrict__ b, float* __restrict__ out)
{
    int t = blockIdx.x * 256 + threadIdx.x;
    int n = t >> 1, l = t & 1;
    if (n >= NN) return;
    float s = 0.f;
    const ushort* hp = h + (size_t)n * 128;
#pragma unroll 8
    for (int k = 0; k < 128; ++k) s = fmaf(bf2f(hp[k]), W[k*2 + l], s);
    s += b[l];
    out[(size_t)n*2 + l] = 1.f / (1.f + __expf(-s));
}

// ---------------------------------------------------------------- launch
extern "C" void kernel_launch(void* const* d_in, const int* in_sizes, int n_in,
                              void* d_out, int out_size, void* d_ws, size_t ws_size,
                              hipStream_t stream)
{
    const float* x    = (const float*)d_in[0];
    const int*   esrc = (const int*)  d_in[1];
    const int*   edst = (const int*)  d_in[2];
    const float* ew   = (const float*)d_in[3];
    const float* preW = (const float*)d_in[4];
    const float* preb = (const float*)d_in[5];
    const float* f1W  = (const float*)d_in[6];
    const float* f1b  = (const float*)d_in[7];
    const float* f2W  = (const float*)d_in[8];
    const float* f2b  = (const float*)d_in[9];
    const float* gW   = (const float*)d_in[10];
    const float* gb   = (const float*)d_in[11];
    const float* fgW  = (const float*)d_in[12];
    const float* fgb  = (const float*)d_in[13];
    const float* l1W  = (const float*)d_in[14];
    const float* l1b  = (const float*)d_in[15];
    const float* l2W  = (const float*)d_in[16];
    const float* l2b  = (const float*)d_in[17];
    float* out = (float*)d_out;

    // workspace layout (bf16 activations + bf16 transposed weights + CSR)
    ushort* wt   = (ushort*)d_ws;
    ushort* wf1  = wt;                          //   4096
    ushort* wf2  = wf1 + 4096;                  //   4096
    ushort* wg   = wf2 + 4096;                  //  98304
    ushort* wfg  = wg  + 98304;                 // 196608
    ushort* wl1  = wfg + 196608;                //  32768
    ushort* h0b  = wl1 + 32768;                 // N*32
    ushort* nidb = h0b  + (size_t)NN * 32;      // N*128
    ushort* hb   = nidb + (size_t)NN * 128;
    ushort* hwb  = hb   + (size_t)NN * 128;
    ushort* aggb = hwb  + (size_t)NN * 128;
    ushort* endu = aggb + (size_t)NN * 128;
    float* sw    = (float*)(((uintptr_t)endu + 15) & ~(uintptr_t)15);
    int*   ssrc  = (int*)(sw + NE);
    int*   deg   = ssrc + NE;
    int*   off   = deg + NN;
    int*   cursor= off + NN + 1;
    int*   bsum  = cursor + NN;                 // 64

    const int gblocks = (NN + 63) / 64;         // 782
    const int eblocks = (NE + 255) / 256;

    convert_weights<<<(335872 + 255) / 256, 256, 0, stream>>>(f1W, f2W, gW, fgW, l1W, wt);

    // ---- CSR build (reused by all 6 layers) ----
    hipMemsetAsync(deg, 0, (size_t)NN * sizeof(int), stream);
    hipMemsetAsync(cursor, 0, (size_t)NN * sizeof(int), stream);
    hist_kernel<<<eblocks, 256, 0, stream>>>(edst, deg);
    scan1_kernel<<<SCAN_BLOCKS, 1024, 0, stream>>>(deg, off, bsum);
    scan2_kernel<<<1, 64, 0, stream>>>(bsum);
    scan3_kernel<<<SCAN_BLOCKS, 1024, 0, stream>>>(off, bsum);
    permute_kernel<<<eblocks, 256, 0, stream>>>(esrc, edst, ew, off, cursor, ssrc, sw);

    // ---- network ----
    preproc_kernel<<<(NN + 255) / 256, 256, 0, stream>>>(x, preW, preb, h0b);
    gemm_mfma<<<gblocks, 256, 0, stream>>>(h0b, 32, nullptr, 0, wf1, f1b, 1, nidb, NN);
    gemm_mfma<<<gblocks, 256, 0, stream>>>(h0b, 32, nullptr, 0, wf2, f2b, 1, hb, NN);
    for (int l = 0; l < 6; ++l) {
        gemm_mfma<<<gblocks, 256, 0, stream>>>(hb, 128, nullptr, 0,
                                               wg + (size_t)l * 16384, nullptr, 0, hwb, NN);
        gather_agg<<<(int)(((long long)NN * 32 + 255) / 256), 256, 0, stream>>>(
            hwb, ssrc, sw, off, gb + (size_t)l * 128, aggb);
        gemm_mfma<<<gblocks, 256, 0, stream>>>(nidb, 128, aggb, 128,
                                               wfg + (size_t)l * 32768,
                                               fgb + (size_t)l * 128, 1, hb, NN);
    }
    gemm_mfma<<<gblocks, 256, 0, stream>>>(nidb, 128, hb, 128, wl1, l1b, 1, hwb, NN);
    last2_kernel<<<(NN * 2 + 255) / 256, 256, 0, stream>>>(hwb, l2W, l2b, out);
}

// Round 4
// 604.487 us; speedup vs baseline: 11.2683x; 1.0570x over previous
//
#include <hip/hip_runtime.h>
#include <cstddef>
#include <cstdint>

#define NN 50000
#define NE 600000
#define SCAN_BLOCKS ((NN + 1023) / 1024)   // 49

typedef __attribute__((ext_vector_type(8))) short bf16x8;
typedef __attribute__((ext_vector_type(4))) float f32x4;

__device__ __forceinline__ float bf2f(ushort u) {
    return __uint_as_float(((uint32_t)u) << 16);
}
__device__ __forceinline__ ushort f2bf(float f) {   // round-to-nearest-even
    uint32_t b = __float_as_uint(f);
    return (ushort)((b + 0x7FFF + ((b >> 16) & 1)) >> 16);
}

// ---------------------------------------------------------------- weights->bf16 transposed
// Wt[c][k] layouts: wf1[128][32] wf2[128][32] wg[l][128][128] wfg[l][128][256] wl1[128][256]
__global__ __launch_bounds__(256)
void convert_weights(const float* __restrict__ f1W, const float* __restrict__ f2W,
                     const float* __restrict__ gW, const float* __restrict__ fgW,
                     const float* __restrict__ l1W, ushort* __restrict__ wt)
{
    int i = blockIdx.x * 256 + threadIdx.x;          // 0 .. 335871
    if (i >= 335872) return;
    float v;
    if (i < 4096) {                                  // wf1
        int c = i >> 5, k = i & 31;
        v = f1W[k * 128 + c];
    } else if (i < 8192) {                           // wf2
        int j = i - 4096; int c = j >> 5, k = j & 31;
        v = f2W[k * 128 + c];
    } else if (i < 8192 + 98304) {                   // wg
        int j = i - 8192; int l = j >> 14, r = j & 16383;
        int c = r >> 7, k = r & 127;
        v = gW[l * 16384 + k * 128 + c];
    } else if (i < 8192 + 98304 + 196608) {          // wfg
        int j = i - (8192 + 98304); int l = j >> 15, r = j & 32767;
        int c = r >> 8, k = r & 255;
        v = fgW[l * 32768 + k * 128 + c];
    } else {                                         // wl1
        int j = i - (8192 + 98304 + 196608);
        int c = j >> 8, k = j & 255;
        v = l1W[k * 128 + c];
    }
    wt[i] = f2bf(v);
}

// ---------------------------------------------------------------- preproc (out bf16)
__global__ __launch_bounds__(256)
void preproc_kernel(const float* __restrict__ x, const float* __restrict__ W,
                    const float* __restrict__ b, ushort* __restrict__ out)
{
    __shared__ float Wl[512];
    __shared__ float bl[32];
    int tx = threadIdx.x;
    Wl[tx]       = W[tx];
    Wl[tx + 256] = W[tx + 256];
    if (tx < 32) bl[tx] = b[tx];
    __syncthreads();
    int n = blockIdx.x * 256 + tx;
    if (n >= NN) return;
    float xr[16];
    const float4* xp = (const float4*)(x + (size_t)n * 16);
#pragma unroll
    for (int q = 0; q < 4; ++q) {
        float4 v = xp[q];
        xr[q*4+0]=v.x; xr[q*4+1]=v.y; xr[q*4+2]=v.z; xr[q*4+3]=v.w;
    }
    float acc[32];
#pragma unroll
    for (int c = 0; c < 32; ++c) acc[c] = bl[c];
#pragma unroll
    for (int k = 0; k < 16; ++k)
#pragma unroll
        for (int c = 0; c < 32; ++c)
            acc[c] = fmaf(xr[k], Wl[k*32+c], acc[c]);
    ushort4* op = (ushort4*)(out + (size_t)n * 32);
#pragma unroll
    for (int q = 0; q < 8; ++q) {
        ushort4 v;
        v.x = f2bf(fmaxf(acc[q*4+0], 0.f));
        v.y = f2bf(fmaxf(acc[q*4+1], 0.f));
        v.z = f2bf(fmaxf(acc[q*4+2], 0.f));
        v.w = f2bf(fmaxf(acc[q*4+3], 0.f));
        op[q] = v;
    }
}

// ---------------------------------------------------------------- MFMA GEMM v3
// out[n][c] = act( [A1|A2][n][:] @ Wt[c][:]^T + bias[c] ), c<128, bf16 in/out.
// Block = 64 rows x 128 cols, 2 waves; wave = 32 rows x 128 cols:
// per K-chunk 10 ds_read_b128 : 16 MFMA (LDS/MFMA pipes balanced).
// XOR chunk swizzle slot = q ^ ((m^(m>>2))&3): frag reads 2-way (free).
__global__ __launch_bounds__(128)
void gemm_mfma(const ushort* __restrict__ A1, int K1,
               const ushort* __restrict__ A2, int K2,
               const ushort* __restrict__ Wt, const float* __restrict__ bias,
               int do_relu, ushort* __restrict__ out, int nrows)
{
    __shared__ ushort Atile[64 * 32];    // 4 KB
    __shared__ ushort Btile[128 * 32];   // 8 KB
    const int tx   = threadIdx.x;
    const int wave = tx >> 6;            // 0..1
    const int lane = tx & 63;
    const int bm   = blockIdx.x * 64;
    const int Ktot = K1 + K2;

    // store-side: lane l of a wave lands at seg_base + l*16B; LDS slot = l&3,
    // row-within-16 = l>>2; fetch global chunk chn = swz(row, slot).
    const int rs  = lane >> 2;                       // 0..15
    const int chn = (lane & 3) ^ ((rs ^ (rs >> 2)) & 3);

    // read-side frag addressing
    const int m    = lane & 15;
    const int quad = lane >> 4;
    const int slot = quad ^ ((m ^ (m >> 2)) & 3);

    f32x4 acc0[8], acc1[8];
#pragma unroll
    for (int t = 0; t < 8; ++t) {
        acc0[t] = (f32x4){0.f, 0.f, 0.f, 0.f};
        acc1[t] = (f32x4){0.f, 0.f, 0.f, 0.f};
    }

    for (int kk = 0; kk < Ktot; kk += 32) {
        const ushort* asrc; int astr, kl;
        if (kk < K1) { asrc = A1; astr = K1; kl = kk; }
        else         { asrc = A2; astr = K2; kl = kk - K1; }
        // A: 4 wave-segments of 16 rows (2 issues/wave)
#pragma unroll
        for (int i = 0; i < 2; ++i) {
            int seg = wave + 2 * i;                  // 0..3
            int row = seg * 16 + rs;                 // 0..63
            int ar  = bm + row; if (ar >= nrows) ar = nrows - 1;
            __builtin_amdgcn_global_load_lds(
                (const __attribute__((address_space(1))) void*)
                    (asrc + (size_t)ar * astr + kl + chn * 8),
                (__attribute__((address_space(3))) void*)(Atile + seg * 512),
                16, 0, 0);
        }
        // B: 8 wave-segments of 16 cols (4 issues/wave)
#pragma unroll
        for (int i = 0; i < 4; ++i) {
            int seg = wave + 2 * i;                  // 0..7
            int col = seg * 16 + rs;                 // 0..127
            __builtin_amdgcn_global_load_lds(
                (const __attribute__((address_space(1))) void*)
                    (Wt + (size_t)col * Ktot + kk + chn * 8),
                (__attribute__((address_space(3))) void*)(Btile + seg * 512),
                16, 0, 0);
        }
        __syncthreads();
        bf16x8 af0 = *(const bf16x8*)(Atile + (wave * 32 + m) * 32 + slot * 8);
        bf16x8 af1 = *(const bf16x8*)(Atile + (wave * 32 + 16 + m) * 32 + slot * 8);
#pragma unroll
        for (int t = 0; t < 8; ++t) {
            bf16x8 bfr = *(const bf16x8*)(Btile + (t * 16 + m) * 32 + slot * 8);
            acc0[t] = __builtin_amdgcn_mfma_f32_16x16x32_bf16(af0, bfr, acc0[t], 0, 0, 0);
            acc1[t] = __builtin_amdgcn_mfma_f32_16x16x32_bf16(af1, bfr, acc1[t], 0, 0, 0);
        }
        __syncthreads();
    }

    // epilogue: C/D layout col=lane&15, row=quad*4+reg
#pragma unroll
    for (int half = 0; half < 2; ++half) {
        const int orow0 = bm + wave * 32 + half * 16 + quad * 4;
#pragma unroll
        for (int t = 0; t < 8; ++t) {
            int col = t * 16 + m;
            float bb = bias ? bias[col] : 0.f;
            f32x4 a = half ? acc1[t] : acc0[t];
#pragma unroll
            for (int r = 0; r < 4; ++r) {
                int row = orow0 + r;
                if (row < nrows) {
                    float v = a[r] + bb;
                    if (do_relu) v = fmaxf(v, 0.f);
                    out[(size_t)row * 128 + col] = f2bf(v);
                }
            }
        }
    }
}

// ---------------------------------------------------------------- CSR build
__global__ __launch_bounds__(256)
void hist_kernel(const int* __restrict__ dst, int* __restrict__ deg)
{
    int e = blockIdx.x * 256 + threadIdx.x;
    if (e < NE) atomicAdd(&deg[dst[e]], 1);
}

__global__ __launch_bounds__(1024)
void scan1_kernel(const int* __restrict__ deg, int* __restrict__ off,
                  int* __restrict__ bsum)
{
    __shared__ int buf[1024];
    int tx = threadIdx.x;
    int i = blockIdx.x * 1024 + tx;
    int v = (i < NN) ? deg[i] : 0;
    buf[tx] = v;
    __syncthreads();
    for (int s = 1; s < 1024; s <<= 1) {
        int t = (tx >= s) ? buf[tx - s] : 0;
        __syncthreads();
        buf[tx] += t;
        __syncthreads();
    }
    if (i < NN) off[i] = buf[tx] - v;
    if (tx == 1023) bsum[blockIdx.x] = buf[1023];
}

__global__ __launch_bounds__(64)
void scan2_kernel(int* __restrict__ bsum)
{
    __shared__ int buf[64];
    int tx = threadIdx.x;
    int v = (tx < SCAN_BLOCKS) ? bsum[tx] : 0;
    buf[tx] = v;
    __syncthreads();
    for (int s = 1; s < 64; s <<= 1) {
        int t = (tx >= s) ? buf[tx - s] : 0;
        __syncthreads();
        buf[tx] += t;
        __syncthreads();
    }
    if (tx < SCAN_BLOCKS) bsum[tx] = buf[tx] - v;
}

__global__ __launch_bounds__(1024)
void scan3_kernel(int* __restrict__ off, const int* __restrict__ bsum)
{
    int i = blockIdx.x * 1024 + threadIdx.x;
    if (i < NN) off[i] += bsum[blockIdx.x];
    if (i == 0) off[NN] = NE;
}

// interleaved (src, weight-bits) single 8B store per edge
__global__ __launch_bounds__(256)
void permute_kernel(const int* __restrict__ src, const int* __restrict__ dst,
                    const float* __restrict__ w, const int* __restrict__ off,
                    int* __restrict__ cursor, int2* __restrict__ esw)
{
    int e = blockIdx.x * 256 + threadIdx.x;
    if (e >= NE) return;
    int d = dst[e];
    int p = off[d] + atomicAdd(&cursor[d], 1);
    esw[p] = make_int2(src[e], __float_as_int(w[e]));
}

// ---------------------------------------------------------------- gather agg
// aggb[n][c] = bf16( relu( sum_e w[e]*hwb[src[e]][c] + gbias[c] ) )
// 16 lanes/node x 8 channels; 16B row loads; edge loop unrolled by 2.
__global__ __launch_bounds__(256)
void gather_agg(const ushort* __restrict__ hwb, const int2* __restrict__ esw,
                const int* __restrict__ off, const float* __restrict__ gbias,
                ushort* __restrict__ aggb)
{
    int t = blockIdx.x * 256 + threadIdx.x;
    int n = t >> 4;
    if (n >= NN) return;
    int lane = t & 15;
    const ushort* hp = hwb + lane * 8;
    int e0 = off[n], e1 = off[n + 1];
    float acc[8];
#pragma unroll
    for (int j = 0; j < 8; ++j) acc[j] = 0.f;
    int e = e0;
    for (; e + 1 < e1; e += 2) {
        int2 p0 = esw[e];
        int2 p1 = esw[e + 1];
        float w0 = __int_as_float(p0.y);
        float w1 = __int_as_float(p1.y);
        bf16x8 v0 = *(const bf16x8*)(hp + (size_t)p0.x * 128);
        bf16x8 v1 = *(const bf16x8*)(hp + (size_t)p1.x * 128);
#pragma unroll
        for (int j = 0; j < 8; ++j)
            acc[j] += bf2f((ushort)v0[j]) * w0 + bf2f((ushort)v1[j]) * w1;
    }
    if (e < e1) {
        int2 p0 = esw[e];
        float w0 = __int_as_float(p0.y);
        bf16x8 v0 = *(const bf16x8*)(hp + (size_t)p0.x * 128);
#pragma unroll
        for (int j = 0; j < 8; ++j)
            acc[j] += bf2f((ushort)v0[j]) * w0;
    }
    int c0 = lane * 8;
    bf16x8 o;
#pragma unroll
    for (int j = 0; j < 8; ++j)
        o[j] = (short)f2bf(fmaxf(acc[j] + gbias[c0 + j], 0.f));
    *(bf16x8*)(aggb + (size_t)n * 128 + c0) = o;
}

// ---------------------------------------------------------------- last2
__global__ __launch_bounds__(256)
void last2_kernel(const ushort* __restrict__ h, const float* __restrict__ W,
                  const float* __restrict__ b, float* __restrict__ out)
{
    int t = blockIdx.x * 256 + threadIdx.x;
    int n = t >> 1, l = t & 1;
    if (n >= NN) return;
    float s = 0.f;
    const ushort* hp = h + (size_t)n * 128;
#pragma unroll 8
    for (int k = 0; k < 128; ++k) s = fmaf(bf2f(hp[k]), W[k*2 + l], s);
    s += b[l];
    out[(size_t)n*2 + l] = 1.f / (1.f + __expf(-s));
}

// ---------------------------------------------------------------- launch
extern "C" void kernel_launch(void* const* d_in, const int* in_sizes, int n_in,
                              void* d_out, int out_size, void* d_ws, size_t ws_size,
                              hipStream_t stream)
{
    const float* x    = (const float*)d_in[0];
    const int*   esrc = (const int*)  d_in[1];
    const int*   edst = (const int*)  d_in[2];
    const float* ew   = (const float*)d_in[3];
    const float* preW = (const float*)d_in[4];
    const float* preb = (const float*)d_in[5];
    const float* f1W  = (const float*)d_in[6];
    const float* f1b  = (const float*)d_in[7];
    const float* f2W  = (const float*)d_in[8];
    const float* f2b  = (const float*)d_in[9];
    const float* gW   = (const float*)d_in[10];
    const float* gb   = (const float*)d_in[11];
    const float* fgW  = (const float*)d_in[12];
    const float* fgb  = (const float*)d_in[13];
    const float* l1W  = (const float*)d_in[14];
    const float* l1b  = (const float*)d_in[15];
    const float* l2W  = (const float*)d_in[16];
    const float* l2b  = (const float*)d_in[17];
    float* out = (float*)d_out;

    // workspace layout (bf16 activations + bf16 transposed weights + CSR)
    ushort* wt   = (ushort*)d_ws;
    ushort* wf1  = wt;                          //   4096
    ushort* wf2  = wf1 + 4096;                  //   4096
    ushort* wg   = wf2 + 4096;                  //  98304
    ushort* wfg  = wg  + 98304;                 // 196608
    ushort* wl1  = wfg + 196608;                //  32768
    ushort* h0b  = wl1 + 32768;                 // N*32
    ushort* nidb = h0b  + (size_t)NN * 32;      // N*128
    ushort* hb   = nidb + (size_t)NN * 128;
    ushort* hwb  = hb   + (size_t)NN * 128;
    ushort* aggb = hwb  + (size_t)NN * 128;
    ushort* endu = aggb + (size_t)NN * 128;
    int2*  esw   = (int2*)(((uintptr_t)endu + 15) & ~(uintptr_t)15);  // E int2
    int*   deg   = (int*)(esw + NE);
    int*   off   = deg + NN;
    int*   cursor= off + NN + 1;
    int*   bsum  = cursor + NN;                 // 64

    const int gblocks = (NN + 63) / 64;         // 782
    const int eblocks = (NE + 255) / 256;

    convert_weights<<<(335872 + 255) / 256, 256, 0, stream>>>(f1W, f2W, gW, fgW, l1W, wt);

    // ---- CSR build (reused by all 6 layers) ----
    hipMemsetAsync(deg, 0, (size_t)NN * sizeof(int), stream);
    hipMemsetAsync(cursor, 0, (size_t)NN * sizeof(int), stream);
    hist_kernel<<<eblocks, 256, 0, stream>>>(edst, deg);
    scan1_kernel<<<SCAN_BLOCKS, 1024, 0, stream>>>(deg, off, bsum);
    scan2_kernel<<<1, 64, 0, stream>>>(bsum);
    scan3_kernel<<<SCAN_BLOCKS, 1024, 0, stream>>>(off, bsum);
    permute_kernel<<<eblocks, 256, 0, stream>>>(esrc, edst, ew, off, cursor, esw);

    // ---- network ----
    preproc_kernel<<<(NN + 255) / 256, 256, 0, stream>>>(x, preW, preb, h0b);
    gemm_mfma<<<gblocks, 128, 0, stream>>>(h0b, 32, nullptr, 0, wf1, f1b, 1, nidb, NN);
    gemm_mfma<<<gblocks, 128, 0, stream>>>(h0b, 32, nullptr, 0, wf2, f2b, 1, hb, NN);
    for (int l = 0; l < 6; ++l) {
        gemm_mfma<<<gblocks, 128, 0, stream>>>(hb, 128, nullptr, 0,
                                               wg + (size_t)l * 16384, nullptr, 0, hwb, NN);
        gather_agg<<<(int)(((long long)NN * 16 + 255) / 256), 256, 0, stream>>>(
            hwb, esw, off, gb + (size_t)l * 128, aggb);
        gemm_mfma<<<gblocks, 128, 0, stream>>>(nidb, 128, aggb, 128,
                                               wfg + (size_t)l * 32768,
                                               fgb + (size_t)l * 128, 1, hb, NN);
    }
    gemm_mfma<<<gblocks, 128, 0, stream>>>(nidb, 128, hb, 128, wl1, l1b, 1, hwb, NN);
    last2_kernel<<<(NN * 2 + 255) / 256, 256, 0, stream>>>(hwb, l2W, l2b, out);
}

// Round 5
// 580.591 us; speedup vs baseline: 11.7320x; 1.0412x over previous
//
#include <hip/hip_runtime.h>
#include <cstddef>
#include <cstdint>

#define NN 50000
#define NE 600000
#define SCAN_BLOCKS ((NN + 1023) / 1024)   // 49

typedef __attribute__((ext_vector_type(8))) short bf16x8;
typedef __attribute__((ext_vector_type(4))) float f32x4;

#define SWZ(x) (((x) ^ ((x) >> 2)) & 3)

__device__ __forceinline__ float bf2f(ushort u) {
    return __uint_as_float(((uint32_t)u) << 16);
}
__device__ __forceinline__ ushort f2bf(float f) {   // round-to-nearest-even
    uint32_t b = __float_as_uint(f);
    return (ushort)((b + 0x7FFF + ((b >> 16) & 1)) >> 16);
}

// ---------------------------------------------------------------- weights->bf16 transposed
// Wt[c][k] layouts: wf1[128][32] wf2[128][32] wg[l][128][128] wfg[l][128][256] wl1[128][256]
__global__ __launch_bounds__(256)
void convert_weights(const float* __restrict__ f1W, const float* __restrict__ f2W,
                     const float* __restrict__ gW, const float* __restrict__ fgW,
                     const float* __restrict__ l1W, ushort* __restrict__ wt)
{
    int i = blockIdx.x * 256 + threadIdx.x;          // 0 .. 335871
    if (i >= 335872) return;
    float v;
    if (i < 4096) {                                  // wf1
        int c = i >> 5, k = i & 31;
        v = f1W[k * 128 + c];
    } else if (i < 8192) {                           // wf2
        int j = i - 4096; int c = j >> 5, k = j & 31;
        v = f2W[k * 128 + c];
    } else if (i < 8192 + 98304) {                   // wg
        int j = i - 8192; int l = j >> 14, r = j & 16383;
        int c = r >> 7, k = r & 127;
        v = gW[l * 16384 + k * 128 + c];
    } else if (i < 8192 + 98304 + 196608) {          // wfg
        int j = i - (8192 + 98304); int l = j >> 15, r = j & 32767;
        int c = r >> 8, k = r & 255;
        v = fgW[l * 32768 + k * 128 + c];
    } else {                                         // wl1
        int j = i - (8192 + 98304 + 196608);
        int c = j >> 8, k = j & 255;
        v = l1W[k * 128 + c];
    }
    wt[i] = f2bf(v);
}

// ---------------------------------------------------------------- preproc (out bf16)
__global__ __launch_bounds__(256)
void preproc_kernel(const float* __restrict__ x, const float* __restrict__ W,
                    const float* __restrict__ b, ushort* __restrict__ out)
{
    __shared__ float Wl[512];
    __shared__ float bl[32];
    int tx = threadIdx.x;
    Wl[tx]       = W[tx];
    Wl[tx + 256] = W[tx + 256];
    if (tx < 32) bl[tx] = b[tx];
    __syncthreads();
    int n = blockIdx.x * 256 + tx;
    if (n >= NN) return;
    float xr[16];
    const float4* xp = (const float4*)(x + (size_t)n * 16);
#pragma unroll
    for (int q = 0; q < 4; ++q) {
        float4 v = xp[q];
        xr[q*4+0]=v.x; xr[q*4+1]=v.y; xr[q*4+2]=v.z; xr[q*4+3]=v.w;
    }
    float acc[32];
#pragma unroll
    for (int c = 0; c < 32; ++c) acc[c] = bl[c];
#pragma unroll
    for (int k = 0; k < 16; ++k)
#pragma unroll
        for (int c = 0; c < 32; ++c)
            acc[c] = fmaf(xr[k], Wl[k*32+c], acc[c]);
    ushort4* op = (ushort4*)(out + (size_t)n * 32);
#pragma unroll
    for (int q = 0; q < 8; ++q) {
        ushort4 v;
        v.x = f2bf(fmaxf(acc[q*4+0], 0.f));
        v.y = f2bf(fmaxf(acc[q*4+1], 0.f));
        v.z = f2bf(fmaxf(acc[q*4+2], 0.f));
        v.w = f2bf(fmaxf(acc[q*4+3], 0.f));
        op[q] = v;
    }
}

// ---------------------------------------------------------------- plain MFMA GEMM (fc_in1)
__global__ __launch_bounds__(128)
void gemm_mfma(const ushort* __restrict__ A1, int K1,
               const ushort* __restrict__ Wt, const float* __restrict__ bias,
               ushort* __restrict__ out, int nrows)
{
    __shared__ ushort Atile[64 * 32];
    __shared__ ushort Btile[128 * 32];
    const int tx   = threadIdx.x;
    const int wave = tx >> 6;
    const int lane = tx & 63;
    const int bm   = blockIdx.x * 64;
    const int Ktot = K1;

    const int rs  = lane >> 2;
    const int chn = (lane & 3) ^ SWZ(rs);
    const int m    = lane & 15;
    const int quad = lane >> 4;
    const int slot = quad ^ SWZ(m);

    f32x4 acc0[8], acc1[8];
#pragma unroll
    for (int t = 0; t < 8; ++t) {
        acc0[t] = (f32x4){0.f, 0.f, 0.f, 0.f};
        acc1[t] = (f32x4){0.f, 0.f, 0.f, 0.f};
    }

    for (int kk = 0; kk < Ktot; kk += 32) {
#pragma unroll
        for (int i = 0; i < 2; ++i) {
            int seg = wave + 2 * i;
            int row = seg * 16 + rs;
            int ar  = bm + row; if (ar >= nrows) ar = nrows - 1;
            __builtin_amdgcn_global_load_lds(
                (const __attribute__((address_space(1))) void*)
                    (A1 + (size_t)ar * K1 + kk + chn * 8),
                (__attribute__((address_space(3))) void*)(Atile + seg * 512),
                16, 0, 0);
        }
#pragma unroll
        for (int i = 0; i < 4; ++i) {
            int seg = wave + 2 * i;
            int col = seg * 16 + rs;
            __builtin_amdgcn_global_load_lds(
                (const __attribute__((address_space(1))) void*)
                    (Wt + (size_t)col * Ktot + kk + chn * 8),
                (__attribute__((address_space(3))) void*)(Btile + seg * 512),
                16, 0, 0);
        }
        __syncthreads();
        bf16x8 af0 = *(const bf16x8*)(Atile + (wave * 32 + m) * 32 + slot * 8);
        bf16x8 af1 = *(const bf16x8*)(Atile + (wave * 32 + 16 + m) * 32 + slot * 8);
#pragma unroll
        for (int t = 0; t < 8; ++t) {
            bf16x8 bfr = *(const bf16x8*)(Btile + (t * 16 + m) * 32 + slot * 8);
            acc0[t] = __builtin_amdgcn_mfma_f32_16x16x32_bf16(af0, bfr, acc0[t], 0, 0, 0);
            acc1[t] = __builtin_amdgcn_mfma_f32_16x16x32_bf16(af1, bfr, acc1[t], 0, 0, 0);
        }
        __syncthreads();
    }

#pragma unroll
    for (int half = 0; half < 2; ++half) {
        const int orow0 = bm + wave * 32 + half * 16 + quad * 4;
#pragma unroll
        for (int t = 0; t < 8; ++t) {
            int col = t * 16 + m;
            float bb = bias[col];
            f32x4 a = half ? acc1[t] : acc0[t];
#pragma unroll
            for (int r = 0; r < 4; ++r) {
                int row = orow0 + r;
                if (row < nrows)
                    out[(size_t)row * 128 + col] = f2bf(fmaxf(a[r] + bb, 0.f));
            }
        }
    }
}

// ---------------------------------------------------------------- fused GEMM
// X = relu([A1|A2] @ Wt^T + bias)   (64 rows in LDS, swizzled A-layout)
// out_hw = X @ Wg^T                 (K=128, no bias/act)
__global__ __launch_bounds__(128)
void gemm_fused(const ushort* __restrict__ A1, int K1,
                const ushort* __restrict__ A2, int K2,
                const ushort* __restrict__ Wt, const float* __restrict__ bias,
                const ushort* __restrict__ Wg,
                ushort* __restrict__ out_hw, int nrows)
{
    __shared__ ushort Atile[64 * 32];
    __shared__ ushort Btile[128 * 32];
    __shared__ ushort Xt[64 * 128];
    const int tx   = threadIdx.x;
    const int wave = tx >> 6;
    const int lane = tx & 63;
    const int bm   = blockIdx.x * 64;
    const int Ktot = K1 + K2;

    const int rs  = lane >> 2;
    const int chn = (lane & 3) ^ SWZ(rs);
    const int m    = lane & 15;
    const int quad = lane >> 4;
    const int slot = quad ^ SWZ(m);

    f32x4 acc0[8], acc1[8];
#pragma unroll
    for (int t = 0; t < 8; ++t) {
        acc0[t] = (f32x4){0.f, 0.f, 0.f, 0.f};
        acc1[t] = (f32x4){0.f, 0.f, 0.f, 0.f};
    }

    // ---- stage 1 ----
    for (int kk = 0; kk < Ktot; kk += 32) {
        const ushort* asrc; int astr, kl;
        if (kk < K1) { asrc = A1; astr = K1; kl = kk; }
        else         { asrc = A2; astr = K2; kl = kk - K1; }
#pragma unroll
        for (int i = 0; i < 2; ++i) {
            int seg = wave + 2 * i;
            int row = seg * 16 + rs;
            int ar  = bm + row; if (ar >= nrows) ar = nrows - 1;
            __builtin_amdgcn_global_load_lds(
                (const __attribute__((address_space(1))) void*)
                    (asrc + (size_t)ar * astr + kl + chn * 8),
                (__attribute__((address_space(3))) void*)(Atile + seg * 512),
                16, 0, 0);
        }
#pragma unroll
        for (int i = 0; i < 4; ++i) {
            int seg = wave + 2 * i;
            int col = seg * 16 + rs;
            __builtin_amdgcn_global_load_lds(
                (const __attribute__((address_space(1))) void*)
                    (Wt + (size_t)col * Ktot + kk + chn * 8),
                (__attribute__((address_space(3))) void*)(Btile + seg * 512),
                16, 0, 0);
        }
        __syncthreads();
        bf16x8 af0 = *(const bf16x8*)(Atile + (wave * 32 + m) * 32 + slot * 8);
        bf16x8 af1 = *(const bf16x8*)(Atile + (wave * 32 + 16 + m) * 32 + slot * 8);
#pragma unroll
        for (int t = 0; t < 8; ++t) {
            bf16x8 bfr = *(const bf16x8*)(Btile + (t * 16 + m) * 32 + slot * 8);
            acc0[t] = __builtin_amdgcn_mfma_f32_16x16x32_bf16(af0, bfr, acc0[t], 0, 0, 0);
            acc1[t] = __builtin_amdgcn_mfma_f32_16x16x32_bf16(af1, bfr, acc1[t], 0, 0, 0);
        }
        __syncthreads();
    }

    // ---- epilogue 1: bias+relu -> Xt (swizzled A-layout), zero acc ----
#pragma unroll
    for (int half = 0; half < 2; ++half) {
        int rbase = wave * 32 + half * 16 + quad * 4;
#pragma unroll
        for (int t = 0; t < 8; ++t) {
            int col = t * 16 + m;
            float bb = bias[col];
            int c32 = col >> 5, within = col & 7, ks = (col >> 3) & 3;
            f32x4 a = half ? acc1[t] : acc0[t];
#pragma unroll
            for (int r = 0; r < 4; ++r) {
                int row = rbase + r;
                int pos = ks ^ SWZ(row & 15);
                Xt[row * 128 + c32 * 32 + pos * 8 + within] =
                    f2bf(fmaxf(a[r] + bb, 0.f));
            }
        }
    }
#pragma unroll
    for (int t = 0; t < 8; ++t) {
        acc0[t] = (f32x4){0.f, 0.f, 0.f, 0.f};
        acc1[t] = (f32x4){0.f, 0.f, 0.f, 0.f};
    }
    __syncthreads();

    // ---- stage 2: out_hw = X @ Wg^T (K=128) ----
    for (int c32 = 0; c32 < 4; ++c32) {
        int kk = c32 * 32;
#pragma unroll
        for (int i = 0; i < 4; ++i) {
            int seg = wave + 2 * i;
            int col = seg * 16 + rs;
            __builtin_amdgcn_global_load_lds(
                (const __attribute__((address_space(1))) void*)
                    (Wg + (size_t)col * 128 + kk + chn * 8),
                (__attribute__((address_space(3))) void*)(Btile + seg * 512),
                16, 0, 0);
        }
        __syncthreads();
        bf16x8 af0 = *(const bf16x8*)(Xt + (wave * 32 + m) * 128 + kk + slot * 8);
        bf16x8 af1 = *(const bf16x8*)(Xt + (wave * 32 + 16 + m) * 128 + kk + slot * 8);
#pragma unroll
        for (int t = 0; t < 8; ++t) {
            bf16x8 bfr = *(const bf16x8*)(Btile + (t * 16 + m) * 32 + slot * 8);
            acc0[t] = __builtin_amdgcn_mfma_f32_16x16x32_bf16(af0, bfr, acc0[t], 0, 0, 0);
            acc1[t] = __builtin_amdgcn_mfma_f32_16x16x32_bf16(af1, bfr, acc1[t], 0, 0, 0);
        }
        __syncthreads();
    }

    // ---- epilogue 2 ----
#pragma unroll
    for (int half = 0; half < 2; ++half) {
        const int orow0 = bm + wave * 32 + half * 16 + quad * 4;
#pragma unroll
        for (int t = 0; t < 8; ++t) {
            int col = t * 16 + m;
            f32x4 a = half ? acc1[t] : acc0[t];
#pragma unroll
            for (int r = 0; r < 4; ++r) {
                int row = orow0 + r;
                if (row < nrows)
                    out_hw[(size_t)row * 128 + col] = f2bf(a[r]);
            }
        }
    }
}

// ---------------------------------------------------------------- last fused
// X = relu(nid@Wfg5_t + agg@Wfg5_b + b5); HH = relu(nid@l1t + X@l1b + l1bias);
// out = sigmoid(HH @ l2W + l2b)  (fp32, direct to d_out)
__global__ __launch_bounds__(128)
void gemm_last(const ushort* __restrict__ nid, const ushort* __restrict__ agg,
               const ushort* __restrict__ Wt, const float* __restrict__ bias5,
               const ushort* __restrict__ Wl1, const float* __restrict__ l1b,
               const float* __restrict__ l2W, const float* __restrict__ l2b,
               float* __restrict__ out, int nrows)
{
    __shared__ ushort Atile[64 * 32];
    __shared__ ushort Btile[128 * 32];
    __shared__ ushort Xt[64 * 128];
    __shared__ float  w2s[256];
    const int tx   = threadIdx.x;
    const int wave = tx >> 6;
    const int lane = tx & 63;
    const int bm   = blockIdx.x * 64;

    w2s[tx]       = l2W[tx];
    w2s[tx + 128] = l2W[tx + 128];

    const int rs  = lane >> 2;
    const int chn = (lane & 3) ^ SWZ(rs);
    const int m    = lane & 15;
    const int quad = lane >> 4;
    const int slot = quad ^ SWZ(m);

    f32x4 acc0[8], acc1[8];
#pragma unroll
    for (int t = 0; t < 8; ++t) {
        acc0[t] = (f32x4){0.f, 0.f, 0.f, 0.f};
        acc1[t] = (f32x4){0.f, 0.f, 0.f, 0.f};
    }

    // ---- stage 1: X = relu(nid@t + agg@b + b5), Ktot=256 ----
    for (int kk = 0; kk < 256; kk += 32) {
        const ushort* asrc; int kl;
        if (kk < 128) { asrc = nid; kl = kk; }
        else          { asrc = agg; kl = kk - 128; }
#pragma unroll
        for (int i = 0; i < 2; ++i) {
            int seg = wave + 2 * i;
            int row = seg * 16 + rs;
            int ar  = bm + row; if (ar >= nrows) ar = nrows - 1;
            __builtin_amdgcn_global_load_lds(
                (const __attribute__((address_space(1))) void*)
                    (asrc + (size_t)ar * 128 + kl + chn * 8),
                (__attribute__((address_space(3))) void*)(Atile + seg * 512),
                16, 0, 0);
        }
#pragma unroll
        for (int i = 0; i < 4; ++i) {
            int seg = wave + 2 * i;
            int col = seg * 16 + rs;
            __builtin_amdgcn_global_load_lds(
                (const __attribute__((address_space(1))) void*)
                    (Wt + (size_t)col * 256 + kk + chn * 8),
                (__attribute__((address_space(3))) void*)(Btile + seg * 512),
                16, 0, 0);
        }
        __syncthreads();
        bf16x8 af0 = *(const bf16x8*)(Atile + (wave * 32 + m) * 32 + slot * 8);
        bf16x8 af1 = *(const bf16x8*)(Atile + (wave * 32 + 16 + m) * 32 + slot * 8);
#pragma unroll
        for (int t = 0; t < 8; ++t) {
            bf16x8 bfr = *(const bf16x8*)(Btile + (t * 16 + m) * 32 + slot * 8);
            acc0[t] = __builtin_amdgcn_mfma_f32_16x16x32_bf16(af0, bfr, acc0[t], 0, 0, 0);
            acc1[t] = __builtin_amdgcn_mfma_f32_16x16x32_bf16(af1, bfr, acc1[t], 0, 0, 0);
        }
        __syncthreads();
    }

    // ---- epilogue 1 -> Xt ----
#pragma unroll
    for (int half = 0; half < 2; ++half) {
        int rbase = wave * 32 + half * 16 + quad * 4;
#pragma unroll
        for (int t = 0; t < 8; ++t) {
            int col = t * 16 + m;
            float bb = bias5[col];
            int c32 = col >> 5, within = col & 7, ks = (col >> 3) & 3;
            f32x4 a = half ? acc1[t] : acc0[t];
#pragma unroll
            for (int r = 0; r < 4; ++r) {
                int row = rbase + r;
                int pos = ks ^ SWZ(row & 15);
                Xt[row * 128 + c32 * 32 + pos * 8 + within] =
                    f2bf(fmaxf(a[r] + bb, 0.f));
            }
        }
    }
#pragma unroll
    for (int t = 0; t < 8; ++t) {
        acc0[t] = (f32x4){0.f, 0.f, 0.f, 0.f};
        acc1[t] = (f32x4){0.f, 0.f, 0.f, 0.f};
    }
    __syncthreads();

    // ---- stage 2: HH = nid@l1t + X@l1b, Ktot=256 ----
    for (int c8 = 0; c8 < 8; ++c8) {
        int kk = c8 * 32;
        if (c8 < 4) {
#pragma unroll
            for (int i = 0; i < 2; ++i) {
                int seg = wave + 2 * i;
                int row = seg * 16 + rs;
                int ar  = bm + row; if (ar >= nrows) ar = nrows - 1;
                __builtin_amdgcn_global_load_lds(
                    (const __attribute__((address_space(1))) void*)
                        (nid + (size_t)ar * 128 + kk + chn * 8),
                    (__attribute__((address_space(3))) void*)(Atile + seg * 512),
                    16, 0, 0);
            }
        }
#pragma unroll
        for (int i = 0; i < 4; ++i) {
            int seg = wave + 2 * i;
            int col = seg * 16 + rs;
            __builtin_amdgcn_global_load_lds(
                (const __attribute__((address_space(1))) void*)
                    (Wl1 + (size_t)col * 256 + kk + chn * 8),
                (__attribute__((address_space(3))) void*)(Btile + seg * 512),
                16, 0, 0);
        }
        __syncthreads();
        bf16x8 af0, af1;
        if (c8 < 4) {
            af0 = *(const bf16x8*)(Atile + (wave * 32 + m) * 32 + slot * 8);
            af1 = *(const bf16x8*)(Atile + (wave * 32 + 16 + m) * 32 + slot * 8);
        } else {
            int ko = (c8 - 4) * 32;
            af0 = *(const bf16x8*)(Xt + (wave * 32 + m) * 128 + ko + slot * 8);
            af1 = *(const bf16x8*)(Xt + (wave * 32 + 16 + m) * 128 + ko + slot * 8);
        }
#pragma unroll
        for (int t = 0; t < 8; ++t) {
            bf16x8 bfr = *(const bf16x8*)(Btile + (t * 16 + m) * 32 + slot * 8);
            acc0[t] = __builtin_amdgcn_mfma_f32_16x16x32_bf16(af0, bfr, acc0[t], 0, 0, 0);
            acc1[t] = __builtin_amdgcn_mfma_f32_16x16x32_bf16(af1, bfr, acc1[t], 0, 0, 0);
        }
        __syncthreads();
    }

    // ---- epilogue: relu(HH+l1b) @ l2W, sigmoid, write fp32 out ----
    float bb[8];
#pragma unroll
    for (int t = 0; t < 8; ++t) bb[t] = l1b[t * 16 + m];
    float b20 = l2b[0], b21 = l2b[1];
#pragma unroll
    for (int half = 0; half < 2; ++half) {
#pragma unroll
        for (int r = 0; r < 4; ++r) {
            float p0 = 0.f, p1 = 0.f;
#pragma unroll
            for (int t = 0; t < 8; ++t) {
                int col = t * 16 + m;
                f32x4 a = half ? acc1[t] : acc0[t];
                float v = fmaxf(a[r] + bb[t], 0.f);
                p0 = fmaf(v, w2s[col * 2 + 0], p0);
                p1 = fmaf(v, w2s[col * 2 + 1], p1);
            }
#pragma unroll
            for (int mask = 1; mask < 16; mask <<= 1) {
                p0 += __shfl_xor(p0, mask);
                p1 += __shfl_xor(p1, mask);
            }
            if (m == 0) {
                int row = bm + wave * 32 + half * 16 + quad * 4 + r;
                if (row < nrows) {
                    out[(size_t)row * 2 + 0] = 1.f / (1.f + __expf(-(p0 + b20)));
                    out[(size_t)row * 2 + 1] = 1.f / (1.f + __expf(-(p1 + b21)));
                }
            }
        }
    }
}

// ---------------------------------------------------------------- CSR build
__global__ __launch_bounds__(256)
void hist_kernel(const int* __restrict__ dst, int* __restrict__ deg)
{
    int e = blockIdx.x * 256 + threadIdx.x;
    if (e < NE) atomicAdd(&deg[dst[e]], 1);
}

__global__ __launch_bounds__(1024)
void scan1_kernel(const int* __restrict__ deg, int* __restrict__ off,
                  int* __restrict__ bsum)
{
    __shared__ int buf[1024];
    int tx = threadIdx.x;
    int i = blockIdx.x * 1024 + tx;
    int v = (i < NN) ? deg[i] : 0;
    buf[tx] = v;
    __syncthreads();
    for (int s = 1; s < 1024; s <<= 1) {
        int t = (tx >= s) ? buf[tx - s] : 0;
        __syncthreads();
        buf[tx] += t;
        __syncthreads();
    }
    if (i < NN) off[i] = buf[tx] - v;
    if (tx == 1023) bsum[blockIdx.x] = buf[1023];
}

__global__ __launch_bounds__(64)
void scan2_kernel(int* __restrict__ bsum)
{
    __shared__ int buf[64];
    int tx = threadIdx.x;
    int v = (tx < SCAN_BLOCKS) ? bsum[tx] : 0;
    buf[tx] = v;
    __syncthreads();
    for (int s = 1; s < 64; s <<= 1) {
        int t = (tx >= s) ? buf[tx - s] : 0;
        __syncthreads();
        buf[tx] += t;
        __syncthreads();
    }
    if (tx < SCAN_BLOCKS) bsum[tx] = buf[tx] - v;
}

__global__ __launch_bounds__(1024)
void scan3_kernel(int* __restrict__ off, const int* __restrict__ bsum)
{
    int i = blockIdx.x * 1024 + threadIdx.x;
    if (i < NN) off[i] += bsum[blockIdx.x];
    if (i == 0) off[NN] = NE;
}

__global__ __launch_bounds__(256)
void permute_kernel(const int* __restrict__ src, const int* __restrict__ dst,
                    const float* __restrict__ w, const int* __restrict__ off,
                    int* __restrict__ cursor, unsigned long long* __restrict__ esw)
{
    int e = blockIdx.x * 256 + threadIdx.x;
    if (e >= NE) return;
    int d = dst[e];
    int p = off[d] + atomicAdd(&cursor[d], 1);
    unsigned long long packed = (unsigned int)src[e] |
        ((unsigned long long)(unsigned int)__float_as_uint(w[e]) << 32);
    __builtin_nontemporal_store(packed, &esw[p]);
}

// ---------------------------------------------------------------- gather (4 channel-phases)
// aggb[n][c] = bf16(relu(sum_e w*hwb[src][c] + gbias[c])); phases of 32 ch keep
// each XCD's hot hwb footprint ~3.2MB (<4MB L2). 4 lanes/node x 8 ch.
__global__ __launch_bounds__(256)
void gather_agg(const ushort* __restrict__ hwb, const int2* __restrict__ esw,
                const int* __restrict__ off, const float* __restrict__ gbias,
                ushort* __restrict__ aggb)
{
    int tx = threadIdx.x;
    int lane4 = tx & 3;
    int n = blockIdx.x * 64 + (tx >> 2);
    if (n >= NN) return;
    int e0 = off[n], e1 = off[n + 1];
#pragma unroll
    for (int phase = 0; phase < 4; ++phase) {
        const ushort* hp = hwb + phase * 32 + lane4 * 8;
        float acc[8];
#pragma unroll
        for (int j = 0; j < 8; ++j) acc[j] = 0.f;
        int e = e0;
        for (; e + 1 < e1; e += 2) {
            int2 p0 = esw[e];
            int2 p1 = esw[e + 1];
            float w0 = __int_as_float(p0.y);
            float w1 = __int_as_float(p1.y);
            bf16x8 v0 = *(const bf16x8*)(hp + (size_t)p0.x * 128);
            bf16x8 v1 = *(const bf16x8*)(hp + (size_t)p1.x * 128);
#pragma unroll
            for (int j = 0; j < 8; ++j)
                acc[j] += bf2f((ushort)v0[j]) * w0 + bf2f((ushort)v1[j]) * w1;
        }
        if (e < e1) {
            int2 p0 = esw[e];
            float w0 = __int_as_float(p0.y);
            bf16x8 v0 = *(const bf16x8*)(hp + (size_t)p0.x * 128);
#pragma unroll
            for (int j = 0; j < 8; ++j)
                acc[j] += bf2f((ushort)v0[j]) * w0;
        }
        int c0 = phase * 32 + lane4 * 8;
        bf16x8 o;
#pragma unroll
        for (int j = 0; j < 8; ++j)
            o[j] = (short)f2bf(fmaxf(acc[j] + gbias[c0 + j], 0.f));
        *(bf16x8*)(aggb + (size_t)n * 128 + c0) = o;
    }
}

// ---------------------------------------------------------------- launch
extern "C" void kernel_launch(void* const* d_in, const int* in_sizes, int n_in,
                              void* d_out, int out_size, void* d_ws, size_t ws_size,
                              hipStream_t stream)
{
    const float* x    = (const float*)d_in[0];
    const int*   esrc = (const int*)  d_in[1];
    const int*   edst = (const int*)  d_in[2];
    const float* ew   = (const float*)d_in[3];
    const float* preW = (const float*)d_in[4];
    const float* preb = (const float*)d_in[5];
    const float* f1W  = (const float*)d_in[6];
    const float* f1b  = (const float*)d_in[7];
    const float* f2W  = (const float*)d_in[8];
    const float* f2b  = (const float*)d_in[9];
    const float* gW   = (const float*)d_in[10];
    const float* gb   = (const float*)d_in[11];
    const float* fgW  = (const float*)d_in[12];
    const float* fgb  = (const float*)d_in[13];
    const float* l1W  = (const float*)d_in[14];
    const float* l1b  = (const float*)d_in[15];
    const float* l2W  = (const float*)d_in[16];
    const float* l2b  = (const float*)d_in[17];
    float* out = (float*)d_out;

    ushort* wt   = (ushort*)d_ws;
    ushort* wf1  = wt;                          //   4096
    ushort* wf2  = wf1 + 4096;                  //   4096
    ushort* wg   = wf2 + 4096;                  //  98304
    ushort* wfg  = wg  + 98304;                 // 196608
    ushort* wl1  = wfg + 196608;                //  32768
    ushort* h0b  = wl1 + 32768;                 // N*32
    ushort* nidb = h0b  + (size_t)NN * 32;      // N*128
    ushort* hwb  = nidb + (size_t)NN * 128;     // N*128
    ushort* aggb = hwb  + (size_t)NN * 128;     // N*128
    ushort* endu = aggb + (size_t)NN * 128;
    unsigned long long* esw = (unsigned long long*)(((uintptr_t)endu + 15) & ~(uintptr_t)15);
    int*   deg   = (int*)(esw + NE);
    int*   off   = deg + NN;
    int*   cursor= off + NN + 1;
    int*   bsum  = cursor + NN;                 // 64

    const int gblocks = (NN + 63) / 64;         // 782
    const int eblocks = (NE + 255) / 256;

    convert_weights<<<(335872 + 255) / 256, 256, 0, stream>>>(f1W, f2W, gW, fgW, l1W, wt);

    // ---- CSR build (reused by all 6 layers) ----
    hipMemsetAsync(deg, 0, (size_t)NN * sizeof(int), stream);
    hipMemsetAsync(cursor, 0, (size_t)NN * sizeof(int), stream);
    hist_kernel<<<eblocks, 256, 0, stream>>>(edst, deg);
    scan1_kernel<<<SCAN_BLOCKS, 1024, 0, stream>>>(deg, off, bsum);
    scan2_kernel<<<1, 64, 0, stream>>>(bsum);
    scan3_kernel<<<SCAN_BLOCKS, 1024, 0, stream>>>(off, bsum);
    permute_kernel<<<eblocks, 256, 0, stream>>>(esrc, edst, ew, off, cursor, esw);

    // ---- network ----
    preproc_kernel<<<(NN + 255) / 256, 256, 0, stream>>>(x, preW, preb, h0b);
    gemm_mfma<<<gblocks, 128, 0, stream>>>(h0b, 32, wf1, f1b, nidb, NN);
    // fc_in2 + gcn0 : hwb = relu(h0@Wf2+b) @ Wg0
    gemm_fused<<<gblocks, 128, 0, stream>>>(h0b, 32, nullptr, 0, wf2, f2b,
                                            wg, hwb, NN);
    for (int l = 0; l < 5; ++l) {
        gather_agg<<<gblocks, 256, 0, stream>>>(hwb, (const int2*)esw, off,
                                                gb + (size_t)l * 128, aggb);
        // fcg_l + gcn_{l+1}
        gemm_fused<<<gblocks, 128, 0, stream>>>(nidb, 128, aggb, 128,
                                                wfg + (size_t)l * 32768,
                                                fgb + (size_t)l * 128,
                                                wg + (size_t)(l + 1) * 16384,
                                                hwb, NN);
    }
    gather_agg<<<gblocks, 256, 0, stream>>>(hwb, (const int2*)esw, off,
                                            gb + (size_t)5 * 128, aggb);
    gemm_last<<<gblocks, 128, 0, stream>>>(nidb, aggb,
                                           wfg + (size_t)5 * 32768,
                                           fgb + (size_t)5 * 128,
                                           wl1, l1b, l2W, l2b, out, NN);
}